// Round 1
// baseline (4223.903 us; speedup 1.0000x reference)
//
#include <hip/hip_runtime.h>
#include <math.h>

// PerceiverResampler on MI355X.
// Strategy: xhat = rownorm(x + frame_emb + media_emb) computed ONCE (bf16);
// per-layer LN affine folded into Wkv (Wkv_f = diag(lnm_w) @ Wkv, kvb = lnm_b @ Wkv).
// All GEMMs bf16 MFMA (16x16x32), fp32 accumulate. Weights pre-transposed to [N][K].
// ws layout (~300 MiB): xhat | kvbuf | per-layer bf16 weights | activations.

#define DIM   1024
#define DEPTH 6
#define HEADS 8
#define NLAT  64
#define INNER 512
#define FFD   4096
#define XROWS 65536
#define LROWS 1024
#define NBT   16

typedef __attribute__((ext_vector_type(8))) short bf16x8;
typedef __attribute__((ext_vector_type(4))) float f32x4;

__device__ __forceinline__ short f2bf(float f) {
  union { float f; unsigned u; } v; v.f = f;
  unsigned r = v.u + 0x7fffu + ((v.u >> 16) & 1u);
  return (short)(r >> 16);
}

__device__ __forceinline__ void gload16(const void* g, void* l) {
  __builtin_amdgcn_global_load_lds(
      (const __attribute__((address_space(1))) unsigned int*)g,
      (__attribute__((address_space(3))) unsigned int*)l, 16, 0, 0);
}

__device__ __forceinline__ f32x4 zero_f4() { f32x4 z; z[0]=0.f; z[1]=0.f; z[2]=0.f; z[3]=0.f; return z; }
__device__ __forceinline__ bf16x8 zero_b8() { bf16x8 z;
#pragma unroll
  for (int e=0;e<8;e++) z[e]=0; return z; }

__device__ __forceinline__ void reduce2(float& s, float& sq, float* sh) {
#pragma unroll
  for (int off = 32; off >= 1; off >>= 1) {
    s  += __shfl_xor(s,  off, 64);
    sq += __shfl_xor(sq, off, 64);
  }
  int t = threadIdx.x;
  if ((t & 63) == 0) { sh[(t >> 6)*2] = s; sh[(t >> 6)*2 + 1] = sq; }
  __syncthreads();
  s  = sh[0] + sh[2] + sh[4] + sh[6];
  sq = sh[1] + sh[3] + sh[5] + sh[7];
}

// ---------------- preprocess: xhat = rownorm(x + fe[f] + me[t]) ----------------
__global__ __launch_bounds__(256)
void prep_kernel(const float* __restrict__ x, const float* __restrict__ fe,
                 const float* __restrict__ me, short* __restrict__ xhat)
{
  __shared__ float sh[8];
  int r = blockIdx.x, t = threadIdx.x;
  int f = (r >> 8) & 15, tt = (r >> 12) & 7;
  float4 xv = ((const float4*)(x + (size_t)r*DIM))[t];
  float4 fv = ((const float4*)(fe + (size_t)f*DIM))[t];
  float4 mv = ((const float4*)(me + (size_t)tt*DIM))[t];
  float y0 = xv.x+fv.x+mv.x, y1 = xv.y+fv.y+mv.y, y2 = xv.z+fv.z+mv.z, y3 = xv.w+fv.w+mv.w;
  float s = y0+y1+y2+y3, sq = y0*y0+y1*y1+y2*y2+y3*y3;
  reduce2(s, sq, sh);
  float mean = s * (1.0f/DIM);
  float var  = sq * (1.0f/DIM) - mean*mean;
  float rs = rsqrtf(var + 1e-5f);
  short4 o; o.x = f2bf((y0-mean)*rs); o.y = f2bf((y1-mean)*rs);
  o.z = f2bf((y2-mean)*rs); o.w = f2bf((y3-mean)*rs);
  ((short4*)(xhat + (size_t)r*DIM))[t] = o;
}

// ---------------- LN over lat rows ----------------
template<bool OBF>
__global__ __launch_bounds__(256)
void ln_kernel(const float* __restrict__ in, const float* __restrict__ w,
               const float* __restrict__ b, void* __restrict__ outp)
{
  __shared__ float sh[8];
  int r = blockIdx.x, t = threadIdx.x;
  float4 xv = ((const float4*)(in + (size_t)r*DIM))[t];
  float s = xv.x+xv.y+xv.z+xv.w;
  float sq = xv.x*xv.x+xv.y*xv.y+xv.z*xv.z+xv.w*xv.w;
  reduce2(s, sq, sh);
  float mean = s*(1.0f/DIM), var = sq*(1.0f/DIM) - mean*mean;
  float rs = rsqrtf(var + 1e-5f);
  float4 wv = ((const float4*)w)[t], bv = ((const float4*)b)[t];
  float o0 = (xv.x-mean)*rs*wv.x + bv.x;
  float o1 = (xv.y-mean)*rs*wv.y + bv.y;
  float o2 = (xv.z-mean)*rs*wv.z + bv.z;
  float o3 = (xv.w-mean)*rs*wv.w + bv.w;
  if (OBF) {
    short4 o; o.x=f2bf(o0); o.y=f2bf(o1); o.z=f2bf(o2); o.w=f2bf(o3);
    ((short4*)((short*)outp + (size_t)r*DIM))[t] = o;
  } else {
    float4 o; o.x=o0; o.y=o1; o.z=o2; o.w=o3;
    ((float4*)((float*)outp + (size_t)r*DIM))[t] = o;
  }
}

// ---------------- lat init: broadcast latents ----------------
__global__ __launch_bounds__(256)
void latinit_kernel(const float* __restrict__ latents, float* __restrict__ lat)
{
  int idx = blockIdx.x * 256 + threadIdx.x;   // float4 index, 262144 total
  int e = idx << 2;
  int row = e >> 10;
  int i = row & 63;
  int col = e & 1023;
  *(float4*)(lat + e) = *(const float4*)(latents + (i << 10) + col);
}

// ---------------- kvb[i][n] = sum_k lnm_b[i][k] * Wkv[i][k][n] ----------------
__global__ __launch_bounds__(256)
void kvb_kernel(const float* __restrict__ lnm_b, const float* __restrict__ Wkv,
                float* __restrict__ kvb)
{
  int i = blockIdx.x, t = threadIdx.x;
  const float* W = Wkv + (size_t)i*DIM*DIM;
  const float* bv = lnm_b + (size_t)i*DIM;
  float acc0=0,acc1=0,acc2=0,acc3=0;
  for (int k = 0; k < DIM; k++) {
    float b = bv[k];
    const float* Wr = W + (size_t)k*DIM;
    acc0 += b * Wr[t];       acc1 += b * Wr[t+256];
    acc2 += b * Wr[t+512];   acc3 += b * Wr[t+768];
  }
  kvb[i*DIM + t]     = acc0; kvb[i*DIM + t+256] = acc1;
  kvb[i*DIM + t+512] = acc2; kvb[i*DIM + t+768] = acc3;
}

// ---------------- transpose-cast: dst[N][K] bf16 = scale * fold[k] * src[K][N] ----------------
__global__ __launch_bounds__(256)
void tcast_kernel(const float* __restrict__ src, short* __restrict__ dst,
                  const float* __restrict__ fold, float scale, int K, int N)
{
  __shared__ float tile[64][65];
  int t = threadIdx.x;
  int n0 = blockIdx.x * 64, k0 = blockIdx.y * 64;
#pragma unroll
  for (int i = 0; i < 16; i++) {
    int rr = (t >> 6) + i*4;
    int cc = t & 63;
    float v = src[(size_t)(k0+rr)*N + n0 + cc] * scale;
    if (fold) v *= fold[k0 + rr];
    tile[rr][cc] = v;
  }
  __syncthreads();
#pragma unroll
  for (int i = 0; i < 16; i++) {
    int nn = (t >> 6) + i*4;
    int kk = t & 63;
    dst[(size_t)(n0+nn)*K + k0 + kk] = f2bf(tile[kk][nn]);
  }
}

// ---------------- GEMM: C[M][N] = A[M][K](bf16) @ Bt[N][K](bf16)  (+bias, epilogue) ----------------
// EPI: 0 = store bf16, 1 = gelu(exact)+store bf16, 2 = accumulate into f32 (C += ..)
template<int EPI, bool HAS_BIAS>
__global__ __launch_bounds__(256, 2)
void gemm_kernel(const short* __restrict__ A, const short* __restrict__ Bt,
                 void* __restrict__ Cout, const float* __restrict__ bias,
                 int M, int N, int K)
{
  __shared__ __align__(16) short As[128*64];
  __shared__ __align__(16) short Bs[128*64];
  const int t = threadIdx.x;
  const int lane = t & 63, w = t >> 6;
  const int m0 = blockIdx.x * 128, n0 = blockIdx.y * 128;
  const int wr = (w >> 1) * 64, wc = (w & 1) * 64;

  f32x4 acc[4][4];
#pragma unroll
  for (int i=0;i<4;i++)
#pragma unroll
    for (int j=0;j<4;j++) acc[i][j] = zero_f4();

  for (int kt = 0; kt < K; kt += 64) {
#pragma unroll
    for (int i = 0; i < 4; i++) {
      int chunk = i*256 + t;            // 0..1023
      int row = chunk >> 3, slot = chunk & 7;
      int ss = slot ^ (row & 7);        // pre-swizzled global source
      gload16(A + (size_t)(m0 + row)*K + kt + ss*8,
              (char*)As + (i*256 + (w<<6))*16);
    }
#pragma unroll
    for (int i = 0; i < 4; i++) {
      int chunk = i*256 + t;
      int row = chunk >> 3, slot = chunk & 7;
      int ss = slot ^ (row & 7);
      gload16(Bt + (size_t)(n0 + row)*K + kt + ss*8,
              (char*)Bs + (i*256 + (w<<6))*16);
    }
    __syncthreads();   // compiler drains vmcnt before barrier

#pragma unroll
    for (int ks = 0; ks < 2; ks++) {
      bf16x8 af[4], bfr[4];
#pragma unroll
      for (int i=0;i<4;i++) {
        int row = wr + i*16 + (lane & 15);
        int slot = (ks*4 + (lane >> 4)) ^ (row & 7);
        af[i] = *(const bf16x8*)((const char*)As + row*128 + slot*16);
        int nrow = wc + i*16 + (lane & 15);
        int nslot = (ks*4 + (lane >> 4)) ^ (nrow & 7);
        bfr[i] = *(const bf16x8*)((const char*)Bs + nrow*128 + nslot*16);
      }
#pragma unroll
      for (int i=0;i<4;i++)
#pragma unroll
        for (int j=0;j<4;j++)
          acc[i][j] = __builtin_amdgcn_mfma_f32_16x16x32_bf16(af[i], bfr[j], acc[i][j], 0, 0, 0);
    }
    __syncthreads();
  }

  const int g = lane >> 4;
#pragma unroll
  for (int i=0;i<4;i++) {
#pragma unroll
    for (int j=0;j<4;j++) {
#pragma unroll
      for (int r=0;r<4;r++) {
        int m = m0 + wr + i*16 + g*4 + r;
        int n = n0 + wc + j*16 + (lane & 15);
        float v = acc[i][j][r];
        if (HAS_BIAS) v += bias[n];
        if (EPI == 0) {
          ((short*)Cout)[(size_t)m*N + n] = f2bf(v);
        } else if (EPI == 1) {
          float gl = 0.5f * v * (1.0f + erff(v * 0.70710678f));
          ((short*)Cout)[(size_t)m*N + n] = f2bf(gl);
        } else {
          float* o = (float*)Cout + (size_t)m*N + n;
          *o += v;
        }
      }
    }
  }
}

// ---------------- fused attention: one block per (bt, head) ----------------
// q: qbuf[bt*64+qi][h*64+dh] (scale pre-folded). keys 0..4095 from kvbuf, 4096..4159 from kvlat.
__global__ __launch_bounds__(256, 1)
void attn_kernel(const short* __restrict__ qbuf, const short* __restrict__ kvbuf,
                 const short* __restrict__ kvlat, short* __restrict__ obuf)
{
  __shared__ __align__(16) short q_sh[64*64];     // [q][dh] swizzled
  __shared__ __align__(16) short K_sh[128*64];    // [key][dh] swizzled
  __shared__ __align__(16) short VT_sh[64*128];   // [dh][key] swizzled
  __shared__ __align__(16) float S_sh[64*132];
  __shared__ __align__(16) short P_sh[64*136];
  __shared__ float red_sh[256];
  __shared__ float alpha_sh[64];
  __shared__ float newm_sh[64];

  const int t = threadIdx.x, lane = t & 63, w = t >> 6;
  const int bt = blockIdx.x >> 3;
  const int h  = blockIdx.x & 7;

  for (int c = t; c < 512; c += 256) {   // stage q (64x64)
    int row = c >> 3, slot = c & 7;
    bf16x8 v = *(const bf16x8*)(qbuf + (size_t)(bt*64 + row)*INNER + h*64 + slot*8);
    *(bf16x8*)((char*)q_sh + row*128 + ((slot ^ (row & 7))*16)) = v;
  }

  float m_run = -1e30f, l_run = 0.f;     // valid for t<64 (row = t)
  f32x4 oacc[4];
#pragma unroll
  for (int j=0;j<4;j++) oacc[j] = zero_f4();

  for (int cc = 0; cc < 33; cc++) {
    __syncthreads();
    const int valid = (cc < 32) ? 128 : 64;
    const short* kbase = (cc < 32)
        ? (kvbuf + ((size_t)bt*4096 + cc*128)*DIM + h*64)
        : (kvlat + ((size_t)bt*64)*DIM + h*64);
    const short* vbase = kbase + INNER;

    for (int c = t; c < 1024; c += 256) {   // stage K chunk
      int row = c >> 3, slot = c & 7;
      bf16x8 v = (row < valid) ? *(const bf16x8*)(kbase + (size_t)row*DIM + slot*8) : zero_b8();
      *(bf16x8*)((char*)K_sh + row*128 + ((slot ^ (row & 7))*16)) = v;
    }
    for (int c = t; c < 1024; c += 256) {   // stage V^T chunk
      int row = c >> 3, slot = c & 7;       // row = key, slot*8.. = dh
      bf16x8 v = (row < valid) ? *(const bf16x8*)(vbase + (size_t)row*DIM + slot*8) : zero_b8();
      int kslot = row >> 3;
#pragma unroll
      for (int e=0;e<8;e++) {
        int dh = slot*8 + e;
        VT_sh[dh*128 + ((kslot ^ (dh & 7))*8) + (row & 7)] = v[e];
      }
    }
    __syncthreads();

    { // S = q @ K^T ; wave w owns q rows 16w..16w+15, all 128 key cols
      f32x4 sacc[8];
#pragma unroll
      for (int j=0;j<8;j++) sacc[j] = zero_f4();
#pragma unroll
      for (int ks=0; ks<2; ks++) {
        int arow = w*16 + (lane & 15);
        int aslot = (ks*4 + (lane >> 4)) ^ (arow & 7);
        bf16x8 af = *(const bf16x8*)((const char*)q_sh + arow*128 + aslot*16);
#pragma unroll
        for (int j=0;j<8;j++) {
          int brow = j*16 + (lane & 15);
          int bslot = (ks*4 + (lane >> 4)) ^ (brow & 7);
          bf16x8 bv = *(const bf16x8*)((const char*)K_sh + brow*128 + bslot*16);
          sacc[j] = __builtin_amdgcn_mfma_f32_16x16x32_bf16(af, bv, sacc[j], 0, 0, 0);
        }
      }
      int rbase = w*16 + (lane >> 4)*4;
#pragma unroll
      for (int j=0;j<8;j++) {
        int col = j*16 + (lane & 15);
#pragma unroll
        for (int r2=0;r2<4;r2++) S_sh[(rbase + r2)*132 + col] = sacc[j][r2];
      }
    }
    __syncthreads();

    { // partial max
      int row = t & 63, qd = t >> 6;
      float mx = -1e30f;
      for (int c = 0; c < 32; c++) {
        int col = qd*32 + c;
        if (col < valid) mx = fmaxf(mx, S_sh[row*132 + col]);
      }
      red_sh[qd*64 + row] = mx;
    }
    __syncthreads();
    if (t < 64) {
      float cm = fmaxf(fmaxf(red_sh[t], red_sh[64+t]), fmaxf(red_sh[128+t], red_sh[192+t]));
      float nm = fmaxf(m_run, cm);
      float al = __expf(m_run - nm);
      m_run = nm;
      alpha_sh[t] = al;
      newm_sh[t] = nm;
    }
    __syncthreads();
    { // exp + P + partial sums
      int row = t & 63, qd = t >> 6;
      float nm = newm_sh[row];
      float sum = 0.f;
      for (int c = 0; c < 32; c++) {
        int col = qd*32 + c;
        float p = 0.f;
        if (col < valid) { p = __expf(S_sh[row*132 + col] - nm); sum += p; }
        P_sh[row*136 + col] = f2bf(p);
      }
      red_sh[qd*64 + row] = sum;
    }
    __syncthreads();
    if (t < 64)
      l_run = l_run * alpha_sh[t] + (red_sh[t] + red_sh[64+t] + red_sh[128+t] + red_sh[192+t]);
    { // rescale old O by alpha, then accumulate P @ V
      int rbase = w*16 + (lane >> 4)*4;
      float a0 = alpha_sh[rbase], a1 = alpha_sh[rbase+1], a2 = alpha_sh[rbase+2], a3 = alpha_sh[rbase+3];
#pragma unroll
      for (int j=0;j<4;j++) { oacc[j][0]*=a0; oacc[j][1]*=a1; oacc[j][2]*=a2; oacc[j][3]*=a3; }
    }
#pragma unroll
    for (int ks=0; ks<4; ks++) {
      int prow = w*16 + (lane & 15);
      bf16x8 af = *(const bf16x8*)((const char*)P_sh + prow*272 + ks*64 + (lane >> 4)*16);
#pragma unroll
      for (int j=0;j<4;j++) {
        int dh = j*16 + (lane & 15);
        int kslot = (ks*4 + (lane >> 4)) ^ (dh & 7);
        bf16x8 bv = *(const bf16x8*)((const char*)VT_sh + dh*256 + kslot*16);
        oacc[j] = __builtin_amdgcn_mfma_f32_16x16x32_bf16(af, bv, oacc[j], 0, 0, 0);
      }
    }
  }

  __syncthreads();
  if (t < 64) alpha_sh[t] = 1.0f / l_run;
  __syncthreads();
  {
    int rbase = w*16 + (lane >> 4)*4;
    float a0 = alpha_sh[rbase], a1 = alpha_sh[rbase+1], a2 = alpha_sh[rbase+2], a3 = alpha_sh[rbase+3];
#pragma unroll
    for (int j=0;j<4;j++) {
      int col = h*64 + j*16 + (lane & 15);
      size_t base = (size_t)(bt*64) * INNER;
      obuf[base + (size_t)(rbase+0)*INNER + col] = f2bf(oacc[j][0]*a0);
      obuf[base + (size_t)(rbase+1)*INNER + col] = f2bf(oacc[j][1]*a1);
      obuf[base + (size_t)(rbase+2)*INNER + col] = f2bf(oacc[j][2]*a2);
      obuf[base + (size_t)(rbase+3)*INNER + col] = f2bf(oacc[j][3]*a3);
    }
  }
}

// ---------------- launch ----------------
extern "C" void kernel_launch(void* const* d_in, const int* in_sizes, int n_in,
                              void* d_out, int out_size, void* d_ws, size_t ws_size,
                              hipStream_t stream)
{
  (void)in_sizes; (void)n_in; (void)out_size; (void)ws_size;
  const float* x        = (const float*)d_in[0];
  const float* latents  = (const float*)d_in[1];
  const float* frame_e  = (const float*)d_in[2];
  const float* media_e  = (const float*)d_in[3];
  const float* lnm_w    = (const float*)d_in[4];
  const float* lnm_b    = (const float*)d_in[5];
  const float* lnl_w    = (const float*)d_in[6];
  const float* lnl_b    = (const float*)d_in[7];
  const float* Wq       = (const float*)d_in[8];
  const float* Wkv      = (const float*)d_in[9];
  const float* Wo       = (const float*)d_in[10];
  const float* ffln_w   = (const float*)d_in[11];
  const float* ffln_b   = (const float*)d_in[12];
  const float* W1       = (const float*)d_in[13];
  const float* b1       = (const float*)d_in[14];
  const float* W2       = (const float*)d_in[15];
  const float* b2       = (const float*)d_in[16];
  const float* fln_w    = (const float*)d_in[17];
  const float* fln_b    = (const float*)d_in[18];
  float* out = (float*)d_out;

  char* ws = (char*)d_ws;
  size_t off = 0;
  short* xhat   = (short*)(ws + off); off += (size_t)XROWS*DIM*2;   // 128 MiB
  short* kvbuf  = (short*)(ws + off); off += (size_t)XROWS*DIM*2;   // 128 MiB
  short* Wkv_f  = (short*)(ws + off); off += (size_t)DIM*DIM*2;
  short* Wq_h   = (short*)(ws + off); off += (size_t)DIM*INNER*2;
  short* Wkv_h  = (short*)(ws + off); off += (size_t)DIM*DIM*2;
  short* Wo_h   = (short*)(ws + off); off += (size_t)INNER*DIM*2;
  short* W1_h   = (short*)(ws + off); off += (size_t)DIM*FFD*2;
  short* W2_h   = (short*)(ws + off); off += (size_t)FFD*DIM*2;
  float* kvb    = (float*)(ws + off); off += (size_t)DEPTH*DIM*4;
  float* lat    = (float*)(ws + off); off += (size_t)LROWS*DIM*4;
  short* lnlat  = (short*)(ws + off); off += (size_t)LROWS*DIM*2;
  short* qbuf   = (short*)(ws + off); off += (size_t)LROWS*INNER*2;
  short* kvlat  = (short*)(ws + off); off += (size_t)LROWS*DIM*2;
  short* obuf   = (short*)(ws + off); off += (size_t)LROWS*INNER*2;
  short* hbuf   = (short*)(ws + off); off += (size_t)LROWS*DIM*2;
  short* h1     = (short*)(ws + off); off += (size_t)LROWS*FFD*2;

  prep_kernel<<<XROWS, 256, 0, stream>>>(x, frame_e, media_e, xhat);
  latinit_kernel<<<1024, 256, 0, stream>>>(latents, lat);
  kvb_kernel<<<DEPTH, 256, 0, stream>>>(lnm_b, Wkv, kvb);

  for (int i = 0; i < DEPTH; i++) {
    tcast_kernel<<<dim3(DIM/64, DIM/64), 256, 0, stream>>>(Wkv + (size_t)i*DIM*DIM, Wkv_f, lnm_w + i*DIM, 1.0f, DIM, DIM);
    tcast_kernel<<<dim3(INNER/64, DIM/64), 256, 0, stream>>>(Wq + (size_t)i*DIM*INNER, Wq_h, nullptr, 0.125f, DIM, INNER);
    tcast_kernel<<<dim3(DIM/64, DIM/64), 256, 0, stream>>>(Wkv + (size_t)i*DIM*DIM, Wkv_h, nullptr, 1.0f, DIM, DIM);
    tcast_kernel<<<dim3(DIM/64, INNER/64), 256, 0, stream>>>(Wo + (size_t)i*INNER*DIM, Wo_h, nullptr, 1.0f, INNER, DIM);
    tcast_kernel<<<dim3(FFD/64, DIM/64), 256, 0, stream>>>(W1 + (size_t)i*DIM*FFD, W1_h, nullptr, 1.0f, DIM, FFD);
    tcast_kernel<<<dim3(DIM/64, FFD/64), 256, 0, stream>>>(W2 + (size_t)i*FFD*DIM, W2_h, nullptr, 1.0f, FFD, DIM);

    ln_kernel<true><<<LROWS, 256, 0, stream>>>(lat, lnl_w + i*DIM, lnl_b + i*DIM, lnlat);
    gemm_kernel<0,false><<<dim3(LROWS/128, INNER/128), 256, 0, stream>>>(lnlat, Wq_h, qbuf, nullptr, LROWS, INNER, DIM);
    gemm_kernel<0,false><<<dim3(LROWS/128, DIM/128), 256, 0, stream>>>(lnlat, Wkv_h, kvlat, nullptr, LROWS, DIM, DIM);
    gemm_kernel<0,true><<<dim3(XROWS/128, DIM/128), 256, 0, stream>>>(xhat, Wkv_f, kvbuf, kvb + i*DIM, XROWS, DIM, DIM);
    attn_kernel<<<NBT*HEADS, 256, 0, stream>>>(qbuf, kvbuf, kvlat, obuf);
    gemm_kernel<2,false><<<dim3(LROWS/128, DIM/128), 256, 0, stream>>>(obuf, Wo_h, lat, nullptr, LROWS, DIM, INNER);
    ln_kernel<true><<<LROWS, 256, 0, stream>>>(lat, ffln_w + i*DIM, ffln_b + i*DIM, hbuf);
    gemm_kernel<1,true><<<dim3(LROWS/128, FFD/128), 256, 0, stream>>>(hbuf, W1_h, h1, b1 + (size_t)i*FFD, LROWS, FFD, DIM);
    gemm_kernel<2,true><<<dim3(LROWS/128, DIM/128), 256, 0, stream>>>(h1, W2_h, lat, b2 + (size_t)i*DIM, LROWS, DIM, FFD);
  }
  ln_kernel<false><<<LROWS, 256, 0, stream>>>(lat, fln_w, fln_b, out);
}

// Round 2
// 2513.208 us; speedup vs baseline: 1.6807x; 1.6807x over previous
//
#include <hip/hip_runtime.h>
#include <math.h>

// PerceiverResampler on MI355X.
// xhat = rownorm(x + frame_emb + media_emb) once (bf16); per-layer LN affine folded
// into Wkv. All GEMMs bf16 MFMA 16x16x32, fp32 accum, weights pre-transposed [N][K].
// Attention: split-K flash (8 splits per bt*head), register online-softmax, combine pass.

#define DIM   1024
#define DEPTH 6
#define HEADS 8
#define NLAT  64
#define INNER 512
#define FFD   4096
#define XROWS 65536
#define LROWS 1024
#define NBT   16
#define QKVN  1536

typedef __attribute__((ext_vector_type(8))) short bf16x8;
typedef __attribute__((ext_vector_type(4))) float f32x4;

__device__ __forceinline__ short f2bf(float f) {
  union { float f; unsigned u; } v; v.f = f;
  unsigned r = v.u + 0x7fffu + ((v.u >> 16) & 1u);
  return (short)(r >> 16);
}

__device__ __forceinline__ void gload16(const void* g, void* l) {
  __builtin_amdgcn_global_load_lds(
      (const __attribute__((address_space(1))) unsigned int*)g,
      (__attribute__((address_space(3))) unsigned int*)l, 16, 0, 0);
}

__device__ __forceinline__ f32x4 zero_f4() { f32x4 z; z[0]=0.f; z[1]=0.f; z[2]=0.f; z[3]=0.f; return z; }
__device__ __forceinline__ bf16x8 zero_b8() { bf16x8 z;
#pragma unroll
  for (int e=0;e<8;e++) z[e]=0; return z; }

__device__ __forceinline__ void reduce2(float& s, float& sq, float* sh) {
#pragma unroll
  for (int off = 32; off >= 1; off >>= 1) {
    s  += __shfl_xor(s,  off, 64);
    sq += __shfl_xor(sq, off, 64);
  }
  int t = threadIdx.x;
  if ((t & 63) == 0) { sh[(t >> 6)*2] = s; sh[(t >> 6)*2 + 1] = sq; }
  __syncthreads();
  s  = sh[0] + sh[2] + sh[4] + sh[6];
  sq = sh[1] + sh[3] + sh[5] + sh[7];
}

// ---------------- preprocess: xhat = rownorm(x + fe[f] + me[t]) ----------------
__global__ __launch_bounds__(256)
void prep_kernel(const float* __restrict__ x, const float* __restrict__ fe,
                 const float* __restrict__ me, short* __restrict__ xhat)
{
  __shared__ float sh[8];
  int r = blockIdx.x, t = threadIdx.x;
  int f = (r >> 8) & 15, tt = (r >> 12) & 7;
  float4 xv = ((const float4*)(x + (size_t)r*DIM))[t];
  float4 fv = ((const float4*)(fe + (size_t)f*DIM))[t];
  float4 mv = ((const float4*)(me + (size_t)tt*DIM))[t];
  float y0 = xv.x+fv.x+mv.x, y1 = xv.y+fv.y+mv.y, y2 = xv.z+fv.z+mv.z, y3 = xv.w+fv.w+mv.w;
  float s = y0+y1+y2+y3, sq = y0*y0+y1*y1+y2*y2+y3*y3;
  reduce2(s, sq, sh);
  float mean = s * (1.0f/DIM);
  float var  = sq * (1.0f/DIM) - mean*mean;
  float rs = rsqrtf(var + 1e-5f);
  short4 o; o.x = f2bf((y0-mean)*rs); o.y = f2bf((y1-mean)*rs);
  o.z = f2bf((y2-mean)*rs); o.w = f2bf((y3-mean)*rs);
  ((short4*)(xhat + (size_t)r*DIM))[t] = o;
}

// ---------------- LN over rows ----------------
template<bool OBF>
__global__ __launch_bounds__(256)
void ln_kernel(const float* __restrict__ in, const float* __restrict__ w,
               const float* __restrict__ b, void* __restrict__ outp)
{
  __shared__ float sh[8];
  int r = blockIdx.x, t = threadIdx.x;
  float4 xv = ((const float4*)(in + (size_t)r*DIM))[t];
  float s = xv.x+xv.y+xv.z+xv.w;
  float sq = xv.x*xv.x+xv.y*xv.y+xv.z*xv.z+xv.w*xv.w;
  reduce2(s, sq, sh);
  float mean = s*(1.0f/DIM), var = sq*(1.0f/DIM) - mean*mean;
  float rs = rsqrtf(var + 1e-5f);
  float4 wv = ((const float4*)w)[t], bv = ((const float4*)b)[t];
  float o0 = (xv.x-mean)*rs*wv.x + bv.x;
  float o1 = (xv.y-mean)*rs*wv.y + bv.y;
  float o2 = (xv.z-mean)*rs*wv.z + bv.z;
  float o3 = (xv.w-mean)*rs*wv.w + bv.w;
  if (OBF) {
    short4 o; o.x=f2bf(o0); o.y=f2bf(o1); o.z=f2bf(o2); o.w=f2bf(o3);
    ((short4*)((short*)outp + (size_t)r*DIM))[t] = o;
  } else {
    float4 o; o.x=o0; o.y=o1; o.z=o2; o.w=o3;
    ((float4*)((float*)outp + (size_t)r*DIM))[t] = o;
  }
}

// ---------------- lat init ----------------
__global__ __launch_bounds__(256)
void latinit_kernel(const float* __restrict__ latents, float* __restrict__ lat)
{
  int idx = blockIdx.x * 256 + threadIdx.x;
  int e = idx << 2;
  int row = e >> 10;
  int i = row & 63;
  int col = e & 1023;
  *(float4*)(lat + e) = *(const float4*)(latents + (i << 10) + col);
}

// ---------------- kvb[i][n] = sum_k lnm_b[i][k] * Wkv[i][k][n] ----------------
__global__ __launch_bounds__(256)
void kvb_kernel(const float* __restrict__ lnm_b, const float* __restrict__ Wkv,
                float* __restrict__ kvb)
{
  int i = blockIdx.x, t = threadIdx.x;
  const float* W = Wkv + (size_t)i*DIM*DIM;
  const float* bv = lnm_b + (size_t)i*DIM;
  float acc0=0,acc1=0,acc2=0,acc3=0;
  for (int k = 0; k < DIM; k++) {
    float b = bv[k];
    const float* Wr = W + (size_t)k*DIM;
    acc0 += b * Wr[t];       acc1 += b * Wr[t+256];
    acc2 += b * Wr[t+512];   acc3 += b * Wr[t+768];
  }
  kvb[i*DIM + t]     = acc0; kvb[i*DIM + t+256] = acc1;
  kvb[i*DIM + t+512] = acc2; kvb[i*DIM + t+768] = acc3;
}

// ---------------- batched transpose-cast for all 6 per-layer weights ----------------
// blocks: [0,256) Wkv_f(fold)  [256,384) Wq->qkvW rows0-511 (scale 1/8)
// [384,640) Wkv->qkvW rows512-1535  [640,768) Wo  [768,1792) W1  [1792,2816) W2
__global__ __launch_bounds__(256)
void tcast_all_kernel(const float* __restrict__ Wkv, const float* __restrict__ Wq,
                      const float* __restrict__ Wo, const float* __restrict__ W1,
                      const float* __restrict__ W2, const float* __restrict__ lnmw,
                      short* __restrict__ Wkv_f, short* __restrict__ qkvW,
                      short* __restrict__ Wo_h, short* __restrict__ W1_h,
                      short* __restrict__ W2_h)
{
  int b = blockIdx.x;
  const float* src; short* dst; const float* fold = nullptr; float scale = 1.0f;
  int K, N, bx, ntx;
  if (b < 256)      { src=Wkv; dst=Wkv_f; fold=lnmw; K=1024; N=1024; bx=b;      ntx=16; }
  else if (b < 384) { src=Wq;  dst=qkvW;  scale=0.125f; K=1024; N=512; bx=b-256; ntx=8; }
  else if (b < 640) { src=Wkv; dst=qkvW+512*1024; K=1024; N=1024; bx=b-384; ntx=16; }
  else if (b < 768) { src=Wo;  dst=Wo_h;  K=512;  N=1024; bx=b-640; ntx=16; }
  else if (b < 1792){ src=W1;  dst=W1_h;  K=1024; N=4096; bx=b-768; ntx=64; }
  else              { src=W2;  dst=W2_h;  K=4096; N=1024; bx=b-1792; ntx=16; }
  int n0 = (bx % ntx)*64, k0 = (bx / ntx)*64;
  __shared__ float tile[64][65];
  int t = threadIdx.x;
#pragma unroll
  for (int i = 0; i < 16; i++) {
    int rr = (t >> 6) + i*4, cc = t & 63;
    float v = src[(size_t)(k0+rr)*N + n0 + cc] * scale;
    if (fold) v *= fold[k0 + rr];
    tile[rr][cc] = v;
  }
  __syncthreads();
#pragma unroll
  for (int i = 0; i < 16; i++) {
    int nn = (t >> 6) + i*4, kk = t & 63;
    dst[(size_t)(n0+nn)*K + k0 + kk] = f2bf(tile[kk][nn]);
  }
}

// ---------------- GEMM: C[M][N] = A[M][K] @ Bt[N][K] (bf16, fp32 acc) ----------------
// EPI: 0 bf16 store, 1 gelu+bf16, 2 f32 +=, 3 f32 atomicAdd (split-K over blockIdx.z)
template<int EPI, bool HAS_BIAS>
__global__ __launch_bounds__(256, 2)
void gemm_kernel(const short* __restrict__ A, const short* __restrict__ Bt,
                 void* __restrict__ Cout, const float* __restrict__ bias,
                 int M, int N, int K, int ldk)
{
  __shared__ __align__(16) short As[128*64];
  __shared__ __align__(16) short Bs[128*64];
  const int t = threadIdx.x;
  const int lane = t & 63, w = t >> 6;
  const int m0 = blockIdx.x * 128, n0 = blockIdx.y * 128;
  const int wr = (w >> 1) * 64, wc = (w & 1) * 64;
  const short* Ap = A + (size_t)blockIdx.z * K;
  const short* Btp = Bt + (size_t)blockIdx.z * K;

  f32x4 acc[4][4];
#pragma unroll
  for (int i=0;i<4;i++)
#pragma unroll
    for (int j=0;j<4;j++) acc[i][j] = zero_f4();

  for (int kt = 0; kt < K; kt += 64) {
#pragma unroll
    for (int i = 0; i < 4; i++) {
      int chunk = i*256 + t;
      int row = chunk >> 3, slot = chunk & 7;
      int ss = slot ^ (row & 7);
      gload16(Ap + (size_t)(m0 + row)*ldk + kt + ss*8,
              (char*)As + (i*256 + (w<<6))*16);
    }
#pragma unroll
    for (int i = 0; i < 4; i++) {
      int chunk = i*256 + t;
      int row = chunk >> 3, slot = chunk & 7;
      int ss = slot ^ (row & 7);
      gload16(Btp + (size_t)(n0 + row)*ldk + kt + ss*8,
              (char*)Bs + (i*256 + (w<<6))*16);
    }
    __syncthreads();

#pragma unroll
    for (int ks = 0; ks < 2; ks++) {
      bf16x8 af[4], bfr[4];
#pragma unroll
      for (int i=0;i<4;i++) {
        int row = wr + i*16 + (lane & 15);
        int slot = (ks*4 + (lane >> 4)) ^ (row & 7);
        af[i] = *(const bf16x8*)((const char*)As + row*128 + slot*16);
        int nrow = wc + i*16 + (lane & 15);
        int nslot = (ks*4 + (lane >> 4)) ^ (nrow & 7);
        bfr[i] = *(const bf16x8*)((const char*)Bs + nrow*128 + nslot*16);
      }
#pragma unroll
      for (int i=0;i<4;i++)
#pragma unroll
        for (int j=0;j<4;j++)
          acc[i][j] = __builtin_amdgcn_mfma_f32_16x16x32_bf16(af[i], bfr[j], acc[i][j], 0, 0, 0);
    }
    __syncthreads();
  }

  const int g = lane >> 4;
#pragma unroll
  for (int i=0;i<4;i++) {
#pragma unroll
    for (int j=0;j<4;j++) {
#pragma unroll
      for (int r=0;r<4;r++) {
        int m = m0 + wr + i*16 + g*4 + r;
        int n = n0 + wc + j*16 + (lane & 15);
        float v = acc[i][j][r];
        if (EPI == 0) {
          if (HAS_BIAS) v += bias[n];
          ((short*)Cout)[(size_t)m*N + n] = f2bf(v);
        } else if (EPI == 1) {
          if (HAS_BIAS) v += bias[n];
          float gl = 0.5f * v * (1.0f + erff(v * 0.70710678f));
          ((short*)Cout)[(size_t)m*N + n] = f2bf(gl);
        } else if (EPI == 2) {
          if (HAS_BIAS) v += bias[n];
          float* o = (float*)Cout + (size_t)m*N + n;
          *o += v;
        } else {
          if (HAS_BIAS && blockIdx.z == 0) v += bias[n];
          atomicAdd((float*)Cout + (size_t)m*N + n, v);
        }
      }
    }
  }
}

// ---------------- attention pass 1: split-K flash with register softmax ----------------
// grid: 1024 = (bt*8+h)*8 + s.  Splits 0..6: 4 chunks of 128 keys; split 7: 4 chunks + 64 latent keys.
__global__ __launch_bounds__(256, 2)
void attn_part_kernel(const short* __restrict__ qkvlat, const short* __restrict__ kvbuf,
                      float* __restrict__ part_O, float* __restrict__ part_m,
                      float* __restrict__ part_l)
{
  __shared__ __align__(16) short q_sh[64*64];     // [q][dh] swizzled
  __shared__ __align__(16) short K_sh[128*64];    // [key][dh] swizzled
  __shared__ __align__(16) short VT_sh[64*128];   // [dh][key] swizzled
  __shared__ __align__(16) short P_sh[64*132];    // [q][key] stride 132

  const int t = threadIdx.x, lane = t & 63, w = t >> 6;
  const int bid = blockIdx.x;
  const int s = bid & 7, bh = bid >> 3;
  const int h = bh & 7, bt = bh >> 3;

  { // stage q (64 x 64) via global_load_lds, pre-swizzled source
    const short* qsrc = qkvlat + (size_t)(bt*64)*QKVN + h*64;
#pragma unroll
    for (int i = 0; i < 2; i++) {
      int chunk = i*256 + t;
      int row = chunk >> 3, slot = chunk & 7;
      gload16(qsrc + (size_t)row*QKVN + ((slot ^ (row & 7))*8),
              (char*)q_sh + (i*256 + (w<<6))*16);
    }
  }

  float m_run[4], l_run[4];
#pragma unroll
  for (int r=0;r<4;r++){ m_run[r] = -1e30f; l_run[r] = 0.f; }
  f32x4 oacc[4];
#pragma unroll
  for (int j=0;j<4;j++) oacc[j] = zero_f4();

  const int nch = (s == 7) ? 5 : 4;
  for (int c5 = 0; c5 < nch; c5++) {
    __syncthreads();   // prev PV done reading P/VT; q visible after first barrier
    const bool isLat = (c5 == 4);
    const int jv = isLat ? 4 : 8;
    const short* kbase; int kstride, valid;
    if (!isLat) {
      kbase = kvbuf + ((size_t)bt*4096 + (s*4 + c5)*128)*DIM + h*64;
      kstride = DIM; valid = 128;
    } else {
      kbase = qkvlat + (size_t)(bt*64)*QKVN + 512 + h*64;
      kstride = QKVN; valid = 64;
    }
    const short* vbase = kbase + 512;

    // stage K (rows >= valid load garbage; those S-cols are never consumed)
#pragma unroll
    for (int i = 0; i < 4; i++) {
      int chunk = i*256 + t;
      int row = chunk >> 3, slot = chunk & 7;
      gload16(kbase + (size_t)row*kstride + ((slot ^ (row & 7))*8),
              (char*)K_sh + (i*256 + (w<<6))*16);
    }
    // stage V^T (zero guard: garbage V rows would NaN-pollute via P=0 * NaN)
#pragma unroll
    for (int i = 0; i < 4; i++) {
      int c = i*256 + t;
      int row = c >> 3, slot = c & 7;
      bf16x8 v = (row < valid) ? *(const bf16x8*)(vbase + (size_t)row*kstride + slot*8) : zero_b8();
      int kslot = row >> 3;
#pragma unroll
      for (int e=0;e<8;e++) {
        int dh = slot*8 + e;
        VT_sh[dh*128 + ((kslot ^ (dh & 7))*8) + (row & 7)] = v[e];
      }
    }
    __syncthreads();

    // S = q @ K^T : sacc[j] holds rows w*16+(lane>>4)*4+r, col j*16+(lane&15)
    f32x4 sacc[8];
#pragma unroll
    for (int j=0;j<8;j++) sacc[j] = zero_f4();
#pragma unroll
    for (int ks=0; ks<2; ks++) {
      int arow = w*16 + (lane & 15);
      int aslot = (ks*4 + (lane >> 4)) ^ (arow & 7);
      bf16x8 af = *(const bf16x8*)((const char*)q_sh + arow*128 + aslot*16);
#pragma unroll
      for (int j=0;j<8;j++) {
        int brow = j*16 + (lane & 15);
        int bslot = (ks*4 + (lane >> 4)) ^ (brow & 7);
        bf16x8 bv = *(const bf16x8*)((const char*)K_sh + brow*128 + bslot*16);
        sacc[j] = __builtin_amdgcn_mfma_f32_16x16x32_bf16(af, bv, sacc[j], 0, 0, 0);
      }
    }

    // register online softmax: row max/sum via 16-lane-group shfl_xor
    float mx[4];
#pragma unroll
    for (int r=0;r<4;r++) mx[r] = -1e30f;
#pragma unroll
    for (int j=0;j<8;j++) {
      if (j < jv) {
#pragma unroll
        for (int r=0;r<4;r++) mx[r] = fmaxf(mx[r], sacc[j][r]);
      }
    }
#pragma unroll
    for (int m2=1; m2<16; m2<<=1) {
#pragma unroll
      for (int r=0;r<4;r++) mx[r] = fmaxf(mx[r], __shfl_xor(mx[r], m2, 64));
    }
    float alpha[4], rowsum[4];
#pragma unroll
    for (int r=0;r<4;r++) {
      float nm = fmaxf(m_run[r], mx[r]);
      alpha[r] = __expf(m_run[r] - nm);
      m_run[r] = nm;
      rowsum[r] = 0.f;
    }
#pragma unroll
    for (int j=0;j<8;j++) {
#pragma unroll
      for (int r=0;r<4;r++) {
        float p = 0.f;
        if (j < jv) { p = __expf(sacc[j][r] - m_run[r]); rowsum[r] += p; }
        P_sh[(w*16 + (lane>>4)*4 + r)*132 + j*16 + (lane & 15)] = f2bf(p);
      }
    }
#pragma unroll
    for (int m2=1; m2<16; m2<<=1) {
#pragma unroll
      for (int r=0;r<4;r++) rowsum[r] += __shfl_xor(rowsum[r], m2, 64);
    }
#pragma unroll
    for (int r=0;r<4;r++) l_run[r] = l_run[r]*alpha[r] + rowsum[r];
#pragma unroll
    for (int j=0;j<4;j++) {
#pragma unroll
      for (int r=0;r<4;r++) oacc[j][r] *= alpha[r];
    }
    __syncthreads();   // P_sh written by all waves before PV reads

    // O += P @ V
#pragma unroll
    for (int ks=0; ks<4; ks++) {
      int prow = w*16 + (lane & 15);
      bf16x8 af = *(const bf16x8*)((const char*)P_sh + prow*264 + ks*64 + (lane >> 4)*16);
#pragma unroll
      for (int j=0;j<4;j++) {
        int dh = j*16 + (lane & 15);
        int kslot = (ks*4 + (lane >> 4)) ^ (dh & 7);
        bf16x8 bv = *(const bf16x8*)((const char*)VT_sh + dh*256 + kslot*16);
        oacc[j] = __builtin_amdgcn_mfma_f32_16x16x32_bf16(af, bv, oacc[j], 0, 0, 0);
      }
    }
  }

  { // write partials (unnormalized O + running m, l)
    float* Ob = part_O + (size_t)bid*4096;
    int rbase = w*16 + (lane>>4)*4;
#pragma unroll
    for (int j=0;j<4;j++) {
#pragma unroll
      for (int r=0;r<4;r++)
        Ob[(rbase + r)*64 + j*16 + (lane & 15)] = oacc[j][r];
    }
    if ((lane & 15) == 0) {
#pragma unroll
      for (int r=0;r<4;r++) {
        part_m[(size_t)bid*64 + rbase + r] = m_run[r];
        part_l[(size_t)bid*64 + rbase + r] = l_run[r];
      }
    }
  }
}

// ---------------- attention pass 2: combine 8 splits ----------------
__global__ __launch_bounds__(256)
void attn_combine_kernel(const float* __restrict__ part_O, const float* __restrict__ part_m,
                         const float* __restrict__ part_l, short* __restrict__ obuf)
{
  int bh = blockIdx.x, t = threadIdx.x;
  int q = t >> 2, c0 = (t & 3) * 16;
  int bt = bh >> 3, h = bh & 7;
  float m8[8], w8[8];
  float mmax = -1e30f;
#pragma unroll
  for (int s=0;s<8;s++) { m8[s] = part_m[(size_t)(bh*8+s)*64 + q]; mmax = fmaxf(mmax, m8[s]); }
  float lt = 0.f;
#pragma unroll
  for (int s=0;s<8;s++) { w8[s] = __expf(m8[s] - mmax); lt += w8[s] * part_l[(size_t)(bh*8+s)*64 + q]; }
  float inv = 1.0f / lt;
  float4 acc[4];
#pragma unroll
  for (int u=0;u<4;u++) { acc[u].x=0.f; acc[u].y=0.f; acc[u].z=0.f; acc[u].w=0.f; }
#pragma unroll
  for (int s=0;s<8;s++) {
    const float4* Ob = (const float4*)(part_O + ((size_t)(bh*8+s)*64 + q)*64 + c0);
#pragma unroll
    for (int u=0;u<4;u++) {
      float4 v = Ob[u];
      acc[u].x += w8[s]*v.x; acc[u].y += w8[s]*v.y;
      acc[u].z += w8[s]*v.z; acc[u].w += w8[s]*v.w;
    }
  }
  short* ob = obuf + (size_t)(bt*64 + q)*INNER + h*64 + c0;
#pragma unroll
  for (int u=0;u<4;u++) {
    short4 o;
    o.x = f2bf(acc[u].x*inv); o.y = f2bf(acc[u].y*inv);
    o.z = f2bf(acc[u].z*inv); o.w = f2bf(acc[u].w*inv);
    ((short4*)ob)[u] = o;
  }
}

// ---------------- launch ----------------
extern "C" void kernel_launch(void* const* d_in, const int* in_sizes, int n_in,
                              void* d_out, int out_size, void* d_ws, size_t ws_size,
                              hipStream_t stream)
{
  (void)in_sizes; (void)n_in; (void)out_size; (void)ws_size;
  const float* x        = (const float*)d_in[0];
  const float* latents  = (const float*)d_in[1];
  const float* frame_e  = (const float*)d_in[2];
  const float* media_e  = (const float*)d_in[3];
  const float* lnm_w    = (const float*)d_in[4];
  const float* lnm_b    = (const float*)d_in[5];
  const float* lnl_w    = (const float*)d_in[6];
  const float* lnl_b    = (const float*)d_in[7];
  const float* Wq       = (const float*)d_in[8];
  const float* Wkv      = (const float*)d_in[9];
  const float* Wo       = (const float*)d_in[10];
  const float* ffln_w   = (const float*)d_in[11];
  const float* ffln_b   = (const float*)d_in[12];
  const float* W1       = (const float*)d_in[13];
  const float* b1       = (const float*)d_in[14];
  const float* W2       = (const float*)d_in[15];
  const float* b2       = (const float*)d_in[16];
  const float* fln_w    = (const float*)d_in[17];
  const float* fln_b    = (const float*)d_in[18];
  float* out = (float*)d_out;

  char* ws = (char*)d_ws;
  size_t off = 0;
  short* xhat   = (short*)(ws + off); off += (size_t)XROWS*DIM*2;
  short* kvbuf  = (short*)(ws + off); off += (size_t)XROWS*DIM*2;
  short* Wkv_f  = (short*)(ws + off); off += (size_t)DIM*DIM*2;
  short* qkvW   = (short*)(ws + off); off += (size_t)QKVN*DIM*2;
  short* Wo_h   = (short*)(ws + off); off += (size_t)INNER*DIM*2;
  short* W1_h   = (short*)(ws + off); off += (size_t)DIM*FFD*2;
  short* W2_h   = (short*)(ws + off); off += (size_t)FFD*DIM*2;
  float* kvb    = (float*)(ws + off); off += (size_t)DEPTH*DIM*4;
  float* lat    = (float*)(ws + off); off += (size_t)LROWS*DIM*4;
  short* lnlat  = (short*)(ws + off); off += (size_t)LROWS*DIM*2;
  short* qkvlat = (short*)(ws + off); off += (size_t)LROWS*QKVN*2;
  short* obuf   = (short*)(ws + off); off += (size_t)LROWS*INNER*2;
  short* hbuf   = (short*)(ws + off); off += (size_t)LROWS*DIM*2;
  short* h1     = (short*)(ws + off); off += (size_t)LROWS*FFD*2;
  float* part_O = (float*)(ws + off); off += (size_t)1024*64*64*4;
  float* part_m = (float*)(ws + off); off += (size_t)1024*64*4;
  float* part_l = (float*)(ws + off); off += (size_t)1024*64*4;

  prep_kernel<<<XROWS, 256, 0, stream>>>(x, frame_e, media_e, xhat);
  latinit_kernel<<<1024, 256, 0, stream>>>(latents, lat);
  kvb_kernel<<<DEPTH, 256, 0, stream>>>(lnm_b, Wkv, kvb);

  for (int i = 0; i < DEPTH; i++) {
    tcast_all_kernel<<<2816, 256, 0, stream>>>(
        Wkv + (size_t)i*DIM*DIM, Wq + (size_t)i*DIM*INNER, Wo + (size_t)i*INNER*DIM,
        W1 + (size_t)i*DIM*FFD, W2 + (size_t)i*FFD*DIM, lnm_w + (size_t)i*DIM,
        Wkv_f, qkvW, Wo_h, W1_h, W2_h);

    ln_kernel<true><<<LROWS, 256, 0, stream>>>(lat, lnl_w + i*DIM, lnl_b + i*DIM, lnlat);
    gemm_kernel<0,false><<<dim3(LROWS/128, QKVN/128), 256, 0, stream>>>(
        lnlat, qkvW, qkvlat, nullptr, LROWS, QKVN, DIM, DIM);
    gemm_kernel<0,true><<<dim3(XROWS/128, DIM/128), 256, 0, stream>>>(
        xhat, Wkv_f, kvbuf, kvb + i*DIM, XROWS, DIM, DIM, DIM);
    attn_part_kernel<<<1024, 256, 0, stream>>>(qkvlat, kvbuf, part_O, part_m, part_l);
    attn_combine_kernel<<<128, 256, 0, stream>>>(part_O, part_m, part_l, obuf);
    gemm_kernel<2,false><<<dim3(LROWS/128, DIM/128), 256, 0, stream>>>(
        obuf, Wo_h, lat, nullptr, LROWS, DIM, INNER, INNER);
    ln_kernel<true><<<LROWS, 256, 0, stream>>>(lat, ffln_w + i*DIM, ffln_b + i*DIM, hbuf);
    gemm_kernel<1,true><<<dim3(LROWS/128, FFD/128), 256, 0, stream>>>(
        hbuf, W1_h, h1, b1 + (size_t)i*FFD, LROWS, FFD, DIM, DIM);
    gemm_kernel<3,true><<<dim3(LROWS/128, DIM/128, 4), 256, 0, stream>>>(
        h1, W2_h, lat, b2 + (size_t)i*DIM, LROWS, DIM, DIM, FFD);
  }
  ln_kernel<false><<<LROWS, 256, 0, stream>>>(lat, fln_w, fln_b, out);
}